// Round 1
// baseline (545.657 us; speedup 1.0000x reference)
//
#include <hip/hip_runtime.h>
#include <math.h>

// ---------------- problem constants ----------------
namespace {
constexpr int kB  = 64;
constexpr int kN  = 1024;
constexpr int kNP = kB * kN;      // 65536 (b,n) pairs
constexpr int kS  = 12;           // S_LOCAL
constexpr int kH  = 64;           // HIDDEN
constexpr int kP  = 32;           // PATTERN
constexpr int kSG = 6;            // S_GLOBAL

// ---------------- workspace layout (bytes) ----------------
constexpr size_t WS_FUSED = 0;                              // [65536][64] f32 = 16 MB
constexpr size_t WS_BMAT  = (size_t)kNP * 64 * 4;           // [384][128] f32
constexpr size_t WS_CONST = WS_BMAT + (size_t)384 * 128 * 4; // [128] f32
constexpr size_t WS_LMEAN = WS_CONST + 128 * 4;             // [64][32] f32
constexpr size_t WS_GMEAN = WS_LMEAN + (size_t)64 * 32 * 4; // [64][32] f32

// ---------------- LDS layout for main kernel (float offsets) ----------------
constexpr int OFF_WT   = 0;      // Wt  [32][68]  (W_q transposed, stride 68)
constexpr int OFF_HS   = 2176;   // hist[64][68]
constexpr int OFF_QT   = 6528;   // qT  [32][68]  (k x pair, transposed A-tile)
constexpr int OFF_BS   = 8704;   // Bs  [32][132] (k x 128 sim cols)
constexpr int SMEM_F   = 12928;  // 51,712 B -> 3 blocks/CU
// epilogue reuse (after barrier):
constexpr int OFF_SIMT = 0;      // SIMT[128][68] (col-major sims)
constexpr int OFF_ML   = 8704;   // Lmean [64*32]
constexpr int OFF_MG   = 10752;  // Gmean [64*32]
}

// ====================================================================
// prep: Bmat (L + 0.5*G pooled-map), const vec (bias fold), bank means
// ====================================================================
__global__ __launch_bounds__(256) void dcmn_prep(
    const float* __restrict__ Gb,   // [64][6][32]
    const float* __restrict__ Lb,   // [64][12][32]
    const float* __restrict__ bq,   // [32]
    float* __restrict__ Bmat,       // [384][128]
    float* __restrict__ constv,     // [128]
    float* __restrict__ Lmean,      // [64][32]
    float* __restrict__ Gmean)      // [64][32]
{
    const int t = threadIdx.x;
    for (int idx = t; idx < 384 * 128; idx += 256) {
        const int k = idx >> 7, mm = idx & 127;
        const int s = k >> 5, p = k & 31;
        float v;
        if (mm < 64) v = Lb[(mm * kS + s) * kP + p];
        else         v = 0.5f * Gb[((mm - 64) * kSG + (s >> 1)) * kP + p];
        Bmat[idx] = v;
    }
    for (int idx = t; idx < 64 * 32; idx += 256) {
        const int m = idx >> 5, p = idx & 31;
        float al = 0.f, ag = 0.f;
        for (int s = 0; s < kS; s++)  al += Lb[(m * kS + s) * kP + p];
        for (int s = 0; s < kSG; s++) ag += Gb[(m * kSG + s) * kP + p];
        Lmean[idx] = al * (1.f / kS);
        Gmean[idx] = ag * (1.f / kSG);
    }
    __syncthreads();
    if (t < 128) {
        float c = 0.f;
        for (int k = 0; k < 384; k++) c += bq[k & 31] * Bmat[k * 128 + t];
        constv[t] = c;
    }
}

// ====================================================================
// main: per block = 64 pairs. Loop s: stage hist chunk + B chunk,
// q-tile GEMM (K=64), SIM-accumulate GEMM (K=32). Epilogue: softmax+ctx.
// ====================================================================
__global__ __launch_bounds__(256, 3) void dcmn_main(
    const float* __restrict__ hist,   // [65536][12][64]
    const float* __restrict__ Wq,     // [64][32]
    const float* __restrict__ Bmat,   // [384][128]
    const float* __restrict__ constv, // [128]
    const float* __restrict__ Lmean,  // [64][32]
    const float* __restrict__ Gmean,  // [64][32]
    float* __restrict__ fused)        // [65536][64]
{
    __shared__ float sm[SMEM_F];
    const int t   = threadIdx.x;
    const int blk = blockIdx.x;

    // ---- stage W_q transposed: Wt[c][h] ----
    for (int idx = t; idx < 2048; idx += 256) {
        const int c = idx & 31, h = idx >> 5;
        sm[OFF_WT + c * 68 + h] = Wq[h * 32 + c];
    }

    // phase-3 (SIM GEMM) thread tile: 4 rows x 8 cols
    const int r3 = (t & 15) * 4;    // pair rows
    const int c3 = (t >> 4) * 8;    // sim cols (0..127)
    float cq[8];
    *(float4*)&cq[0] = *(const float4*)&constv[c3];
    *(float4*)&cq[4] = *(const float4*)&constv[c3 + 4];

    // phase-2 (q GEMM) thread tile: 4 rows x 2 cols
    const int r2 = (t >> 4) * 4;    // pair rows (wave-uniform-ish: broadcast reads)
    const int c2 = (t & 15) * 2;    // q cols (0..31)

    float acc[4][8];
#pragma unroll
    for (int i = 0; i < 4; i++)
#pragma unroll
        for (int j = 0; j < 8; j++) acc[i][j] = 0.f;

#pragma unroll 1
    for (int s = 0; s < kS; s++) {
        __syncthreads();  // previous iter consumers done before overwrite
        // ---- stage hist chunk [64][64] and B chunk [32][128] ----
        {
            const float4* gp = (const float4*)hist;
#pragma unroll
            for (int i = 0; i < 4; i++) {
                const int idx = t + 256 * i;           // 1024 float4
                const int r = idx >> 4, c4 = idx & 15;
                float4 v = gp[((size_t)(blk * 64 + r) * kS + s) * 16 + c4];
                *(float4*)&sm[OFF_HS + r * 68 + c4 * 4] = v;
            }
            const float4* bp = (const float4*)(Bmat + s * 32 * 128);
#pragma unroll
            for (int i = 0; i < 4; i++) {
                const int idx = t + 256 * i;           // 1024 float4
                const int k = idx >> 5, m4 = idx & 31;
                float4 v = bp[k * 32 + m4];
                *(float4*)&sm[OFF_BS + k * 132 + m4 * 4] = v;
            }
        }
        __syncthreads();

        // ---- phase 2: q[r][c] = sum_h hist[r][h] * W[h][c], write qT[c][r] ----
        {
            float qa0[4] = {0.f, 0.f, 0.f, 0.f};
            float qa1[4] = {0.f, 0.f, 0.f, 0.f};
#pragma unroll 4
            for (int h = 0; h < 64; h += 4) {
                const float4 w0 = *(const float4*)&sm[OFF_WT + c2 * 68 + h];
                const float4 w1 = *(const float4*)&sm[OFF_WT + (c2 + 1) * 68 + h];
#pragma unroll
                for (int i = 0; i < 4; i++) {
                    const float4 hv = *(const float4*)&sm[OFF_HS + (r2 + i) * 68 + h];
                    qa0[i] = fmaf(hv.x, w0.x, qa0[i]);
                    qa0[i] = fmaf(hv.y, w0.y, qa0[i]);
                    qa0[i] = fmaf(hv.z, w0.z, qa0[i]);
                    qa0[i] = fmaf(hv.w, w0.w, qa0[i]);
                    qa1[i] = fmaf(hv.x, w1.x, qa1[i]);
                    qa1[i] = fmaf(hv.y, w1.y, qa1[i]);
                    qa1[i] = fmaf(hv.z, w1.z, qa1[i]);
                    qa1[i] = fmaf(hv.w, w1.w, qa1[i]);
                }
            }
            float4 v0 = {qa0[0], qa0[1], qa0[2], qa0[3]};
            float4 v1 = {qa1[0], qa1[1], qa1[2], qa1[3]};
            *(float4*)&sm[OFF_QT + c2 * 68 + r2]       = v0;
            *(float4*)&sm[OFF_QT + (c2 + 1) * 68 + r2] = v1;
        }
        __syncthreads();

        // ---- phase 3: SIM[r][mm] += sum_k qT[k][r] * Bs[k][mm] ----
#pragma unroll 4
        for (int k = 0; k < 32; k++) {
            const float4 a  = *(const float4*)&sm[OFF_QT + k * 68 + r3];
            const float4 b0 = *(const float4*)&sm[OFF_BS + k * 132 + c3];
            const float4 b1 = *(const float4*)&sm[OFF_BS + k * 132 + c3 + 4];
            const float av[4] = {a.x, a.y, a.z, a.w};
            const float bv[8] = {b0.x, b0.y, b0.z, b0.w, b1.x, b1.y, b1.z, b1.w};
#pragma unroll
            for (int i = 0; i < 4; i++)
#pragma unroll
                for (int j = 0; j < 8; j++)
                    acc[i][j] = fmaf(av[i], bv[j], acc[i][j]);
        }
    }

    __syncthreads();  // all phase-3 LDS reads done; repurpose LDS

    // ---- write sims (bias folded) transposed: SIMT[col][row] ----
#pragma unroll
    for (int j = 0; j < 8; j++) {
        float4 v = {acc[0][j] + cq[j], acc[1][j] + cq[j],
                    acc[2][j] + cq[j], acc[3][j] + cq[j]};
        *(float4*)&sm[OFF_SIMT + (c3 + j) * 68 + r3] = v;
    }
    // ---- stage bank means ----
    for (int idx = t; idx < 512; idx += 256) {  // 512 float4 each
        ((float4*)&sm[OFF_ML])[idx] = ((const float4*)Lmean)[idx];
        ((float4*)&sm[OFF_MG])[idx] = ((const float4*)Gmean)[idx];
    }
    __syncthreads();

    // ---- epilogue: softmax over 64 memories + ctx ----
    // wave-uniform split: wave0 local p0..15, wave1 global p0..15,
    //                     wave2 local p16..31, wave3 global p16..31
    {
        const int r    = t & 63;
        const int qd   = t >> 6;
        const int side = qd & 1;
        const int p0   = (qd >> 1) * 16;
        const float* srow = &sm[OFF_SIMT + side * 64 * 68 + r];  // elem m at m*68
        const float* mean = (side ? &sm[OFF_MG] : &sm[OFF_ML]) + p0;

        float mx = -1e30f;
#pragma unroll 4
        for (int m = 0; m < 64; m++) mx = fmaxf(mx, srow[m * 68]);

        float den = 0.f;
        float4 ctx0 = {0, 0, 0, 0}, ctx1 = {0, 0, 0, 0},
               ctx2 = {0, 0, 0, 0}, ctx3 = {0, 0, 0, 0};
#pragma unroll 4
        for (int m = 0; m < 64; m++) {
            const float w = __expf(srow[m * 68] - mx);
            den += w;
            const float* mr = mean + m * 32;     // wave-uniform -> LDS broadcast
            const float4 m0 = *(const float4*)(mr);
            const float4 m1 = *(const float4*)(mr + 4);
            const float4 m2 = *(const float4*)(mr + 8);
            const float4 m3 = *(const float4*)(mr + 12);
            ctx0.x = fmaf(w, m0.x, ctx0.x); ctx0.y = fmaf(w, m0.y, ctx0.y);
            ctx0.z = fmaf(w, m0.z, ctx0.z); ctx0.w = fmaf(w, m0.w, ctx0.w);
            ctx1.x = fmaf(w, m1.x, ctx1.x); ctx1.y = fmaf(w, m1.y, ctx1.y);
            ctx1.z = fmaf(w, m1.z, ctx1.z); ctx1.w = fmaf(w, m1.w, ctx1.w);
            ctx2.x = fmaf(w, m2.x, ctx2.x); ctx2.y = fmaf(w, m2.y, ctx2.y);
            ctx2.z = fmaf(w, m2.z, ctx2.z); ctx2.w = fmaf(w, m2.w, ctx2.w);
            ctx3.x = fmaf(w, m3.x, ctx3.x); ctx3.y = fmaf(w, m3.y, ctx3.y);
            ctx3.z = fmaf(w, m3.z, ctx3.z); ctx3.w = fmaf(w, m3.w, ctx3.w);
        }
        const float sc = 1.f / den;
        float4* fp = (float4*)&fused[(size_t)(blk * 64 + r) * 64 + side * 32 + p0];
        float4 o0 = {ctx0.x * sc, ctx0.y * sc, ctx0.z * sc, ctx0.w * sc};
        float4 o1 = {ctx1.x * sc, ctx1.y * sc, ctx1.z * sc, ctx1.w * sc};
        float4 o2 = {ctx2.x * sc, ctx2.y * sc, ctx2.z * sc, ctx2.w * sc};
        float4 o3 = {ctx3.x * sc, ctx3.y * sc, ctx3.z * sc, ctx3.w * sc};
        fp[0] = o0; fp[1] = o1; fp[2] = o2; fp[3] = o3;
    }
}

// ====================================================================
// out: per block = one node n. node_w[n] = emb[n] @ pool into LDS,
// then out[b,n,:] = fused[b,n,:] @ node_w[n] for all 64 b.
// ====================================================================
__global__ __launch_bounds__(256) void dcmn_out(
    const float* __restrict__ emb,    // [1024][16]
    const float* __restrict__ pool,   // [16][64][64]
    const float* __restrict__ fused,  // [65536][64]
    float* __restrict__ out)          // [64][1024][64]
{
    __shared__ float nw[64 * 68];   // nodeW [f][h], stride 68
    __shared__ float fs[64 * 68];   // fused [b][f], stride 68
    __shared__ float es[16];
    const int t = threadIdx.x;
    const int n = blockIdx.x;

    if (t < 16) es[t] = emb[n * 16 + t];
    // stage fused rows for all 64 batches
#pragma unroll
    for (int i = 0; i < 4; i++) {
        const int idx = t + 256 * i;             // 1024 float4
        const int b = idx >> 4, c4 = idx & 15;
        float4 v = *(const float4*)&fused[((size_t)b * kN + n) * 64 + c4 * 4];
        *(float4*)&fs[b * 68 + c4 * 4] = v;
    }
    __syncthreads();

    // node_w: 4096 outputs, 16/thread, K=16 (pool is L2-resident)
#pragma unroll
    for (int i = 0; i < 16; i++) {
        const int idx = t + 256 * i;
        const int f = idx >> 6, h = idx & 63;
        float a = 0.f;
#pragma unroll
        for (int d = 0; d < 16; d++)
            a = fmaf(es[d], pool[(d * 64 + f) * 64 + h], a);
        nw[f * 68 + h] = a;
    }
    __syncthreads();

    // out[b][n][h] = sum_f fs[b][f] * nw[f][h]; thread: fixed h, 16 b's
    const int h  = t & 63;
    const int bg = t >> 6;     // 0..3 -> b = bg*16 + bb
    float o[16];
#pragma unroll
    for (int bb = 0; bb < 16; bb++) o[bb] = 0.f;
#pragma unroll 4
    for (int f = 0; f < 64; f++) {
        const float w = nw[f * 68 + h];
#pragma unroll
        for (int bb = 0; bb < 16; bb++)
            o[bb] = fmaf(fs[(bg * 16 + bb) * 68 + f], w, o[bb]);
    }
#pragma unroll
    for (int bb = 0; bb < 16; bb++) {
        const int b = bg * 16 + bb;
        out[((size_t)b * kN + n) * 64 + h] = o[bb];
    }
}

// ====================================================================
extern "C" void kernel_launch(void* const* d_in, const int* in_sizes, int n_in,
                              void* d_out, int out_size, void* d_ws, size_t ws_size,
                              hipStream_t stream) {
    (void)in_sizes; (void)n_in; (void)out_size; (void)ws_size;
    const float* hist = (const float*)d_in[0];   // h_history
    const float* Gb   = (const float*)d_in[1];   // global_memory_bank
    const float* Lb   = (const float*)d_in[2];   // local_memory_bank
    const float* Wq   = (const float*)d_in[3];   // W_q
    const float* bq   = (const float*)d_in[4];   // b_q
    const float* emb  = (const float*)d_in[5];   // node_embedding
    const float* pool = (const float*)d_in[6];   // weight_pool
    float* outp = (float*)d_out;

    char* ws = (char*)d_ws;
    float* fused  = (float*)(ws + WS_FUSED);
    float* Bmat   = (float*)(ws + WS_BMAT);
    float* constv = (float*)(ws + WS_CONST);
    float* Lmean  = (float*)(ws + WS_LMEAN);
    float* Gmean  = (float*)(ws + WS_GMEAN);

    hipLaunchKernelGGL(dcmn_prep, dim3(1), dim3(256), 0, stream,
                       Gb, Lb, bq, Bmat, constv, Lmean, Gmean);
    hipLaunchKernelGGL(dcmn_main, dim3(1024), dim3(256), 0, stream,
                       hist, Wq, Bmat, constv, Lmean, Gmean, fused);
    hipLaunchKernelGGL(dcmn_out, dim3(1024), dim3(256), 0, stream,
                       emb, pool, fused, outp);
}

// Round 4
// 410.412 us; speedup vs baseline: 1.3295x; 1.3295x over previous
//
#include <hip/hip_runtime.h>
#include <hip/hip_bf16.h>
#include <math.h>

// ---------------- problem constants ----------------
namespace {
constexpr int kN  = 1024;
constexpr int kK  = 768;          // 12 * 64 fused K
// workspace layout (bytes)
constexpr size_t WS_FUSED = 0;                               // [65536][64] f32 = 16 MB
constexpr size_t WS_CTH   = (size_t)65536 * 64 * 4;          // [128][768] bf16 hi
constexpr size_t WS_CTL   = WS_CTH + (size_t)128 * 768 * 2;  // [128][768] bf16 lo
constexpr size_t WS_CONST = WS_CTL + (size_t)128 * 768 * 2;  // [128] f32
constexpr size_t WS_LMEAN = WS_CONST + 512;                  // [64][32] f32
constexpr size_t WS_GMEAN = WS_LMEAN + (size_t)64 * 32 * 4;  // [64][32] f32
}

typedef __attribute__((ext_vector_type(4))) float f32x4;
typedef __attribute__((ext_vector_type(8))) short bf16x8;

__device__ __forceinline__ short to_bf16(float f) {
    __hip_bfloat16 h = __float2bfloat16(f);   // RNE
    return *reinterpret_cast<short*>(&h);
}
__device__ __forceinline__ float bf16_to_f32(short s) {
    unsigned u = ((unsigned)(unsigned short)s) << 16;
    return __uint_as_float(u);
}
// exact 2-term split: v = hi + lo + O(2^-18 |v|)
__device__ __forceinline__ void split_bf16(float v, short& hi, short& lo) {
    hi = to_bf16(v);
    lo = to_bf16(v - bf16_to_f32(hi));
}

// ====================================================================
// prep: grid 128 (one block per memory slot mm).
// C[mm][s*64+h] = sum_p W[h,p] * bank[s,p]  -> split into CtH/CtL bf16 planes
// constv[mm] = sum_{s,p} bq[p]*bank[s,p];  bank means.
// ====================================================================
__global__ __launch_bounds__(256) void dcmn_prep(
    const float* __restrict__ Gb,   // [64][6][32]
    const float* __restrict__ Lb,   // [64][12][32]
    const float* __restrict__ Wq,   // [64][32]
    const float* __restrict__ bq,   // [32]
    short* __restrict__ CtH,        // [128][768] bf16 hi
    short* __restrict__ CtL,        // [128][768] bf16 lo
    float* __restrict__ constv,     // [128]
    float* __restrict__ Lmean,      // [64][32]
    float* __restrict__ Gmean)      // [64][32]
{
    __shared__ float Ws[2048];      // W[h][p]
    __shared__ float bank[384];     // [s][p], s=0..11
    const int t = threadIdx.x, mm = blockIdx.x;

    for (int i = t; i < 2048; i += 256) Ws[i] = Wq[i];
    for (int i = t; i < 384; i += 256) {
        const int s = i >> 5, p = i & 31;
        bank[i] = (mm < 64) ? Lb[mm * 384 + i]
                            : 0.5f * Gb[(mm - 64) * 192 + (s >> 1) * 32 + p];
    }
    __syncthreads();

    for (int i = t; i < kK; i += 256) {
        const int s = i >> 6, h = i & 63;
        float a = 0.f;
#pragma unroll
        for (int p = 0; p < 32; p++) a = fmaf(Ws[h * 32 + p], bank[s * 32 + p], a);
        short hi, lo;
        split_bf16(a, hi, lo);
        CtH[(size_t)mm * kK + i] = hi;
        CtL[(size_t)mm * kK + i] = lo;
    }
    if (t < 32) {
        float a = 0.f;
#pragma unroll
        for (int s = 0; s < 12; s++) a += bank[s * 32 + t];
        if (mm < 64) Lmean[mm * 32 + t] = a * (1.f / 12.f);
        else         Gmean[(mm - 64) * 32 + t] = a * (1.f / 6.f);
    }
    if (t == 0) {
        float c = 0.f;
        for (int i = 0; i < 384; i++) c += bq[i & 31] * bank[i];
        constv[mm] = c;
    }
}

// ====================================================================
// main: GEMM [65536,768]@[768,128] in split-bf16 (3 MFMA passes:
// aH*bH + aL*bH + aH*bL) + softmax/ctx epilogue.
// Block = 64 rows x 128 cols, 4 waves; K in 12 chunks of 64.
// LDS tiles are UNPADDED ([row][64] shorts) with XOR swizzle on the
// 8-short group index (g ^= row&7) to break bank aliasing.
// GEMM phase: AsH/AsL 8KB each + BsH/BsL 16KB each = 48KB;
// epilogue reuse needs 50KB -> LDS 51200B -> 3 blocks/CU.
// ====================================================================
__global__ __launch_bounds__(256, 3) void dcmn_main(
    const float* __restrict__ hist,   // [65536][768]
    const short* __restrict__ CtH,    // [128][768] bf16 hi
    const short* __restrict__ CtL,    // [128][768] bf16 lo
    const float* __restrict__ constv, // [128]
    const float* __restrict__ Lmean,  // [64][32]
    const float* __restrict__ Gmean,  // [64][32]
    float* __restrict__ fused)        // [65536][64]
{
    __shared__ char smraw[51200];
    short* AsH = (short*)smraw;              // [64][64]
    short* AsL = (short*)(smraw + 8192);     // [64][64]
    short* BsH = (short*)(smraw + 16384);    // [128][64]
    short* BsL = (short*)(smraw + 32768);    // [128][64]

    const int t = threadIdx.x, blk = blockIdx.x;
    const int wv = t >> 6, ln = t & 63;
    const int l15 = ln & 15, hi = ln >> 4;
    const int swz = l15 & 7;                 // frag-row swizzle (row&7 == l15&7)

    f32x4 acc[8];
#pragma unroll
    for (int i = 0; i < 8; i++) acc[i] = (f32x4){0.f, 0.f, 0.f, 0.f};

    const size_t histBase = (size_t)blk * 64 * kK;
    const int arow = wv * 16 + l15;

#pragma unroll 1
    for (int kc = 0; kc < 12; kc++) {
        __syncthreads();
        // ---- stage A: 64 rows x 64 floats -> split bf16, swizzled ----
#pragma unroll
        for (int i = 0; i < 2; i++) {
            const int c = 2 * t + i;            // 512 groups of 8
            const int r = c >> 3, g = c & 7;
            const float* src = hist + histBase + (size_t)r * kK + kc * 64 + g * 8;
            const float4 v0 = *(const float4*)src;
            const float4 v1 = *(const float4*)(src + 4);
            const float vv[8] = {v0.x, v0.y, v0.z, v0.w, v1.x, v1.y, v1.z, v1.w};
            bf16x8 oh, ol;
#pragma unroll
            for (int e = 0; e < 8; e++) {
                short h8, l8;
                split_bf16(vv[e], h8, l8);
                oh[e] = h8; ol[e] = l8;
            }
            const int dst = r * 64 + ((g ^ (r & 7)) << 3);
            *(bf16x8*)&AsH[dst] = oh;
            *(bf16x8*)&AsL[dst] = ol;
        }
        // ---- stage B: 2 planes x 128 rows x 64 k (int4 copies, swizzled) ----
#pragma unroll
        for (int j = 0; j < 8; j++) {
            const int idx = t + 256 * j;        // 2048 int4
            const int pl  = idx >> 10;          // 0:H 1:L (wave-uniform per j)
            const int rem = idx & 1023;
            const int mm  = rem >> 3, g = rem & 7;
            const short* srcp = (pl ? CtL : CtH) + (size_t)mm * kK + kc * 64 + g * 8;
            short* dstp = (pl ? BsL : BsH) + mm * 64 + ((g ^ (mm & 7)) << 3);
            *(int4*)dstp = *(const int4*)srcp;
        }
        __syncthreads();
        // ---- MFMA: 2 k-steps x 8 col-tiles x 3 passes ----
#pragma unroll
        for (int kk = 0; kk < 2; kk++) {
            const int ag = ((kk * 4 + hi) ^ swz) << 3;
            const bf16x8 aH = *(const bf16x8*)&AsH[arow * 64 + ag];
            const bf16x8 aL = *(const bf16x8*)&AsL[arow * 64 + ag];
#pragma unroll
            for (int ct = 0; ct < 8; ct++) {
                const int brow = ct * 16 + l15;
                const bf16x8 bH = *(const bf16x8*)&BsH[brow * 64 + ag];
                const bf16x8 bL = *(const bf16x8*)&BsL[brow * 64 + ag];
                acc[ct] = __builtin_amdgcn_mfma_f32_16x16x32_bf16(aH, bH, acc[ct], 0, 0, 0);
                acc[ct] = __builtin_amdgcn_mfma_f32_16x16x32_bf16(aL, bH, acc[ct], 0, 0, 0);
                acc[ct] = __builtin_amdgcn_mfma_f32_16x16x32_bf16(aH, bL, acc[ct], 0, 0, 0);
            }
        }
    }

    __syncthreads();   // all MFMA LDS reads done; repurpose LDS
    float* SIMT = (float*)smraw;             // [128][68] (col x row) 34816 B
    float* ML   = (float*)(smraw + 34816);   // [64][32]
    float* MG   = (float*)(smraw + 43008);   // [64][32]

    // ---- write sims + folded bias, transposed: SIMT[col][row] ----
    // C/D layout: col = lane&15, row(16-tile) = (lane>>4)*4 + reg
#pragma unroll
    for (int ct = 0; ct < 8; ct++) {
        const int col = ct * 16 + l15;
        const float cv = constv[col];
        float4 o = {acc[ct][0] + cv, acc[ct][1] + cv, acc[ct][2] + cv, acc[ct][3] + cv};
        *(float4*)&SIMT[col * 68 + wv * 16 + hi * 4] = o;
    }
    for (int i = t; i < 512; i += 256) {
        ((float4*)ML)[i] = ((const float4*)Lmean)[i];
        ((float4*)MG)[i] = ((const float4*)Gmean)[i];
    }
    __syncthreads();

    // ---- epilogue: per-row softmax over 64 memories + ctx ----
    {
        const int r    = t & 63;
        const int qd   = t >> 6;
        const int side = qd & 1;
        const int p0   = (qd >> 1) * 16;
        const float* srow = &SIMT[side * 64 * 68 + r];
        const float* mean = (side ? MG : ML) + p0;

        float mx = -1e30f;
#pragma unroll 4
        for (int m = 0; m < 64; m++) mx = fmaxf(mx, srow[m * 68]);

        float den = 0.f;
        float4 c0 = {0,0,0,0}, c1 = {0,0,0,0}, c2 = {0,0,0,0}, c3 = {0,0,0,0};
#pragma unroll 4
        for (int m = 0; m < 64; m++) {
            const float w = __expf(srow[m * 68] - mx);
            den += w;
            const float* mr = mean + m * 32;     // wave-uniform -> LDS broadcast
            const float4 m0 = *(const float4*)(mr);
            const float4 m1 = *(const float4*)(mr + 4);
            const float4 m2 = *(const float4*)(mr + 8);
            const float4 m3 = *(const float4*)(mr + 12);
            c0.x = fmaf(w, m0.x, c0.x); c0.y = fmaf(w, m0.y, c0.y);
            c0.z = fmaf(w, m0.z, c0.z); c0.w = fmaf(w, m0.w, c0.w);
            c1.x = fmaf(w, m1.x, c1.x); c1.y = fmaf(w, m1.y, c1.y);
            c1.z = fmaf(w, m1.z, c1.z); c1.w = fmaf(w, m1.w, c1.w);
            c2.x = fmaf(w, m2.x, c2.x); c2.y = fmaf(w, m2.y, c2.y);
            c2.z = fmaf(w, m2.z, c2.z); c2.w = fmaf(w, m2.w, c2.w);
            c3.x = fmaf(w, m3.x, c3.x); c3.y = fmaf(w, m3.y, c3.y);
            c3.z = fmaf(w, m3.z, c3.z); c3.w = fmaf(w, m3.w, c3.w);
        }
        const float sc = 1.f / den;
        float4* fp = (float4*)&fused[(size_t)(blk * 64 + r) * 64 + side * 32 + p0];
        float4 o0 = {c0.x*sc, c0.y*sc, c0.z*sc, c0.w*sc};
        float4 o1 = {c1.x*sc, c1.y*sc, c1.z*sc, c1.w*sc};
        float4 o2 = {c2.x*sc, c2.y*sc, c2.z*sc, c2.w*sc};
        float4 o3 = {c3.x*sc, c3.y*sc, c3.z*sc, c3.w*sc};
        fp[0] = o0; fp[1] = o1; fp[2] = o2; fp[3] = o3;
    }
}

// ====================================================================
// out: per block = one node n. nw = emb[n] @ pool (LDS), fused staged
// TRANSPOSED (fsT[f][b]) so inner loop is 2x ds_read_b128 per f.
// ====================================================================
__global__ __launch_bounds__(256) void dcmn_out(
    const float* __restrict__ emb,    // [1024][16]
    const float* __restrict__ pool,   // [16][64][64]
    const float* __restrict__ fused,  // [65536][64]
    float* __restrict__ out)          // [64][1024][64]
{
    __shared__ float nw[64 * 68];    // nodeW [f][h]
    __shared__ float fsT[64 * 68];   // fused transposed [f][b]
    __shared__ float es[16];
    const int t = threadIdx.x, n = blockIdx.x;

    if (t < 16) es[t] = emb[n * 16 + t];
#pragma unroll
    for (int i = 0; i < 4; i++) {
        const int idx = t + 256 * i;             // 1024 float4
        const int b = idx >> 4, c4 = idx & 15;
        const float4 v = *(const float4*)&fused[((size_t)b * kN + n) * 64 + c4 * 4];
        fsT[(c4 * 4 + 0) * 68 + b] = v.x;
        fsT[(c4 * 4 + 1) * 68 + b] = v.y;
        fsT[(c4 * 4 + 2) * 68 + b] = v.z;
        fsT[(c4 * 4 + 3) * 68 + b] = v.w;
    }
    __syncthreads();

    // node_w: 4096 outputs, K=16 (pool L2-resident, coalesced over h)
#pragma unroll
    for (int i = 0; i < 16; i++) {
        const int idx = t + 256 * i;
        const int f = idx >> 6, h = idx & 63;
        float a = 0.f;
#pragma unroll
        for (int d = 0; d < 16; d++)
            a = fmaf(es[d], pool[(d * 64 + f) * 64 + h], a);
        nw[f * 68 + h] = a;
    }
    __syncthreads();

    // out[b][h] = sum_f fsT[f][b] * nw[f][h]; thread tile 4b x 4h
    const int tb = t >> 4;      // b = tb*4 + i
    const int th = t & 15;      // h = th*4 + j  (h fastest -> coalesced stores)
    f32x4 o0 = {0,0,0,0}, o1 = {0,0,0,0}, o2 = {0,0,0,0}, o3 = {0,0,0,0};
#pragma unroll 8
    for (int f = 0; f < 64; f++) {
        const f32x4 a = *(const f32x4*)&fsT[f * 68 + tb * 4];
        const f32x4 w = *(const f32x4*)&nw[f * 68 + th * 4];
        o0 += w * a.x;
        o1 += w * a.y;
        o2 += w * a.z;
        o3 += w * a.w;
    }
    *(f32x4*)&out[((size_t)(tb * 4 + 0) * kN + n) * 64 + th * 4] = o0;
    *(f32x4*)&out[((size_t)(tb * 4 + 1) * kN + n) * 64 + th * 4] = o1;
    *(f32x4*)&out[((size_t)(tb * 4 + 2) * kN + n) * 64 + th * 4] = o2;
    *(f32x4*)&out[((size_t)(tb * 4 + 3) * kN + n) * 64 + th * 4] = o3;
}

// ====================================================================
extern "C" void kernel_launch(void* const* d_in, const int* in_sizes, int n_in,
                              void* d_out, int out_size, void* d_ws, size_t ws_size,
                              hipStream_t stream) {
    (void)in_sizes; (void)n_in; (void)out_size; (void)ws_size;
    const float* hist = (const float*)d_in[0];   // h_history
    const float* Gb   = (const float*)d_in[1];   // global_memory_bank
    const float* Lb   = (const float*)d_in[2];   // local_memory_bank
    const float* Wq   = (const float*)d_in[3];   // W_q
    const float* bq   = (const float*)d_in[4];   // b_q
    const float* emb  = (const float*)d_in[5];   // node_embedding
    const float* pool = (const float*)d_in[6];   // weight_pool
    float* outp = (float*)d_out;

    char* ws = (char*)d_ws;
    float* fused  = (float*)(ws + WS_FUSED);
    short* CtH    = (short*)(ws + WS_CTH);
    short* CtL    = (short*)(ws + WS_CTL);
    float* constv = (float*)(ws + WS_CONST);
    float* Lmean  = (float*)(ws + WS_LMEAN);
    float* Gmean  = (float*)(ws + WS_GMEAN);

    hipLaunchKernelGGL(dcmn_prep, dim3(128), dim3(256), 0, stream,
                       Gb, Lb, Wq, bq, CtH, CtL, constv, Lmean, Gmean);
    hipLaunchKernelGGL(dcmn_main, dim3(1024), dim3(256), 0, stream,
                       hist, CtH, CtL, constv, Lmean, Gmean, fused);
    hipLaunchKernelGGL(dcmn_out, dim3(1024), dim3(256), 0, stream,
                       emb, pool, fused, outp);
}